// Round 5
// baseline (5538.430 us; speedup 1.0000x reference)
//
#include <hip/hip_runtime.h>
#include <float.h>

// FPS: N=524288 pts, M=2048 selected (idx[0]=0), out = pos[idxs] (2048x3 f32).
// 64 cooperative blocks x 1024 threads. Sync-free iteration:
//   wave butterfly -> tag-embedded LDS deposit (parity dbuf) ->
//   wave0 spins on 16 deposits, reduces, publishes tagged global slot ->
//   ONLY wave0 polls the 64 padded slots (hot spin) -> reduces -> loads winner
//   coords (same-address bcast) -> relays via 3 self-validating LDS words ->
//   sibling waves spin on those. No __syncthreads in the loop, no fences:
//   every shared word carries its own monotone tag.

#define NPTS     524288
#define MOUT     2048
#define NBLK     64
#define NTHR     1024
#define NWAVE    (NTHR / 64)            // 16
#define GTHREADS (NBLK * NTHR)          // 65536
#define PPT      (NPTS / GTHREADS)      // 8
#define SLOT_STRIDE 8                   // u64 stride -> 64 B line per publisher
#define MASK51   ((1ull << 51) - 1)

// global slot word: [tag:13][fbits:32][idx_inv:19]
// LDS sred word:    [tag:13][fbits:32][idx_inv:19]   (same packing)
// LDS bcast word k: [tag:32][coord_k_bits:32]
// fbits = IEEE bits of min_d (>=0 so bit order == value order)
// idx_inv = (NPTS-1)-idx: equal values -> smaller idx wins the max
// => first-occurrence tie-break == jnp.argmax (absmax 0.0 R1-R4).

__global__ void __launch_bounds__(NTHR, 1) fps_kernel(
    const float* __restrict__ pos, float* __restrict__ out,
    unsigned long long* __restrict__ slots)
{
    const unsigned tid  = threadIdx.x;
    const unsigned lane = tid & 63u;
    const unsigned wav  = tid >> 6;
    const unsigned blk  = blockIdx.x;
    const unsigned g    = blk * NTHR + tid;

    float X[PPT], Y[PPT], Z[PPT], D[PPT];
#pragma unroll
    for (int p = 0; p < PPT; ++p) {
        const unsigned idx = g + (unsigned)p * GTHREADS;
        X[p] = pos[3u * idx + 0];
        Y[p] = pos[3u * idx + 1];
        Z[p] = pos[3u * idx + 2];
        D[p] = FLT_MAX;
    }

    float px = pos[0], py = pos[1], pz = pos[2];
    if (g == 0) { out[0] = px; out[1] = py; out[2] = pz; }

    // Parity-double-buffered tagged scratch. Tags are the iteration number,
    // monotone and unique -> every word is self-validating, no fences needed.
    __shared__ unsigned long long sred[2][NWAVE];   // per-wave bests
    __shared__ unsigned long long bc[2][3];         // winner coords relay
    if (tid < 2u * NWAVE) ((unsigned long long*)sred)[tid] = 0ull;
    if (tid < 6u)         ((unsigned long long*)bc)[tid]   = 0ull;
    __syncthreads();   // once, outside the loop

    for (int i = 1; i < MOUT; ++i) {
        const unsigned p2 = (unsigned)i & 1u;
        // ---- distance update + per-thread argmax (exact fp32: no FMA,
        // ---- sum order (dx^2+dy^2)+dz^2; absmax==0 verified R1-R4) ----
        float bv = -1.0f;
        unsigned bi = 0;
#pragma unroll
        for (int p = 0; p < PPT; ++p) {
            float dx = __fsub_rn(X[p], px);
            float dy = __fsub_rn(Y[p], py);
            float dz = __fsub_rn(Z[p], pz);
            float d  = __fadd_rn(__fadd_rn(__fmul_rn(dx, dx), __fmul_rn(dy, dy)),
                                 __fmul_rn(dz, dz));
            float m  = fminf(D[p], d);
            D[p] = m;
            if (m > bv) { bv = m; bi = g + (unsigned)p * GTHREADS; }
        }
        unsigned long long best =
            ((unsigned long long)__float_as_uint(bv) << 19) |
            (unsigned long long)((NPTS - 1u) - bi);

        // ---- wave butterfly ----
#pragma unroll
        for (int off = 32; off > 0; off >>= 1) {
            unsigned long long o = __shfl_xor(best, off, 64);
            if (o > best) best = o;
        }

        // ---- deposit tag-embedded wave best (no barrier) ----
        if (lane == 0)
            __hip_atomic_store(&sred[p2][wav],
                               ((unsigned long long)i << 51) | best,
                               __ATOMIC_RELAXED, __HIP_MEMORY_SCOPE_WORKGROUP);

        const unsigned long long tag = (unsigned long long)i;

        if (wav == 0) {
            // ---- gather 16 wave-bests (self-validating) ----
            unsigned long long e;
            do {
                e = __hip_atomic_load(&sred[p2][lane & (NWAVE - 1u)],
                                      __ATOMIC_RELAXED, __HIP_MEMORY_SCOPE_WORKGROUP);
            } while (!__all((e >> 51) == tag));
            unsigned long long b2 = e & MASK51;
#pragma unroll
            for (int off = NWAVE / 2; off > 0; off >>= 1) {   // 8,4,2,1
                unsigned long long o = __shfl_xor(b2, off, 64);
                if (o > b2) b2 = o;
            }

            // ---- publish block best ----
            unsigned long long* buf = slots + p2 * (NBLK * SLOT_STRIDE);
            if (lane == 0)
                __hip_atomic_store(&buf[blk * SLOT_STRIDE], (tag << 51) | b2,
                                   __ATOMIC_RELAXED, __HIP_MEMORY_SCOPE_AGENT);

            // ---- poll all 64 slots, hot spin (only 64 waves device-wide) ----
            unsigned long long s;
            do {
                s = __hip_atomic_load(&buf[lane * SLOT_STRIDE],
                                      __ATOMIC_RELAXED, __HIP_MEMORY_SCOPE_AGENT);
            } while (!__all((s >> 51) == tag));

            unsigned long long win = s & MASK51;
#pragma unroll
            for (int off = 32; off > 0; off >>= 1) {
                unsigned long long o = __shfl_xor(win, off, 64);
                if (o > win) win = o;
            }
            unsigned widx = (NPTS - 1u) - (unsigned)(win & 0x7FFFFull);
            // same-address broadcast loads (one transaction each, L2-hot)
            float x = pos[3u * widx + 0];
            float y = pos[3u * widx + 1];
            float z = pos[3u * widx + 2];
            px = x; py = y; pz = z;
            if (blk == 0 && lane == 0) {
                out[3 * i + 0] = x; out[3 * i + 1] = y; out[3 * i + 2] = z;
            }
            // ---- relay to sibling waves: 3 self-validating words ----
            if (lane < 3u) {
                float c = (lane == 0) ? x : (lane == 1) ? y : z;
                __hip_atomic_store(&bc[p2][lane],
                                   (tag << 32) | (unsigned long long)__float_as_uint(c),
                                   __ATOMIC_RELAXED, __HIP_MEMORY_SCOPE_WORKGROUP);
            }
        } else {
            // ---- sibling waves: spin on the relay words ----
            unsigned long long w0, w1, w2;
            do {
                w0 = __hip_atomic_load(&bc[p2][0], __ATOMIC_RELAXED, __HIP_MEMORY_SCOPE_WORKGROUP);
                w1 = __hip_atomic_load(&bc[p2][1], __ATOMIC_RELAXED, __HIP_MEMORY_SCOPE_WORKGROUP);
                w2 = __hip_atomic_load(&bc[p2][2], __ATOMIC_RELAXED, __HIP_MEMORY_SCOPE_WORKGROUP);
                if ((w0 >> 32) == tag && (w1 >> 32) == tag && (w2 >> 32) == tag) break;
                __builtin_amdgcn_s_sleep(1);
            } while (true);
            px = __uint_as_float((unsigned)(w0 & 0xFFFFFFFFull));
            py = __uint_as_float((unsigned)(w1 & 0xFFFFFFFFull));
            pz = __uint_as_float((unsigned)(w2 & 0xFFFFFFFFull));
        }
    }
}

extern "C" void kernel_launch(void* const* d_in, const int* in_sizes, int n_in,
                              void* d_out, int out_size, void* d_ws, size_t ws_size,
                              hipStream_t stream) {
    const float* pos = (const float*)d_in[0];
    float* out = (float*)d_out;
    unsigned long long* slots = (unsigned long long*)d_ws;  // 2 x 64 x 64B = 8 KB
    // No memset: d_ws is re-poisoned 0xAA each launch; poison decodes to tag
    // 0x1555, never a real tag (1..2047). Monotone tags + parity kill ABA.

    void* args[] = { (void*)&pos, (void*)&out, (void*)&slots };
    hipLaunchCooperativeKernel((void*)fps_kernel, dim3(NBLK), dim3(NTHR),
                               args, 0, stream);
}